// Round 1
// baseline (154.918 us; speedup 1.0000x reference)
//
#include <hip/hip_runtime.h>

namespace {
constexpr int BATCH = 512;
constexpr int SEQL  = 512;
constexpr int HID   = 256;
constexpr int MORPH = 24;
constexpr float NEGV = -1.0e9f;
}

// One block per batch row b. 256 threads = 4 waves.
// Phase 1: scores[l] = dot(we[b,l,:], W) + b0, NEG-masked for l >= wl-1
// Phase 2: exact stable top-(nm-1) selection by rank; c2m via popcount prefix
// Phase 3: bpm one-hot write (float4)
// Phase 4: menc = per-segment running sums (wave per morpheme)
extern "C" __global__ __launch_bounds__(256)
void morphseg_kernel(const float* __restrict__ we,    // [B, L, H]
                     const int*   __restrict__ wlen,  // [B]
                     const int*   __restrict__ nmorph,// [B] (== MORPH here)
                     const float* __restrict__ Wv,    // [H]
                     const float* __restrict__ bias,  // [1]
                     float* __restrict__ out)         // menc [B*M*H] then bpm [B*L*M]
{
    const int b    = blockIdx.x;
    const int tid  = threadIdx.x;
    const int lane = tid & 63;
    const int wave = tid >> 6;

    __shared__ float s_scores[SEQL];
    __shared__ unsigned long long s_ind[8];   // separator bitmask over l
    __shared__ int s_c2m[SEQL];               // #separators strictly before l
    __shared__ int s_sep[MORPH];              // sorted separator positions

    const int wl = wlen[b];
    const int nm = nmorph[b];                 // 24 in this dataset
    const int K  = nm - 1;                    // number of separators
    const float b0 = bias[0];
    const float* werow = we + (size_t)b * (SEQL * HID);

    // ---- Phase 1: scores (wave per row; lane covers h = 4*lane..4*lane+3)
    const float4 w4 = reinterpret_cast<const float4*>(Wv)[lane];
    for (int l = wave; l < SEQL; l += 4) {
        float s = NEGV;
        if (l < wl - 1) {   // wave-uniform branch; masked rows: skip the load entirely
            float4 v = reinterpret_cast<const float4*>(werow + (size_t)l * HID)[lane];
            float p = v.x * w4.x + v.y * w4.y + v.z * w4.z + v.w * w4.w;
            #pragma unroll
            for (int off = 32; off >= 1; off >>= 1)
                p += __shfl_xor(p, off, 64);
            s = p + b0;
        }
        if (lane == 0) s_scores[l] = s;
    }
    __syncthreads();

    // ---- Phase 2: exact stable rank (matches jax.lax.top_k tie-breaking:
    // ties prefer lower index). l is a separator iff rank < K.
    const float sl0 = s_scores[tid];
    const float sl1 = s_scores[tid + 256];
    int c0 = 0, c1 = 0;
    for (int j = 0; j < SEQL; ++j) {
        const float sj = s_scores[j];   // LDS broadcast read
        c0 += (int)(sj > sl0) | ((int)(sj == sl0) & (int)(j < tid));
        c1 += (int)(sj > sl1) | ((int)(sj == sl1) & (int)(j < tid + 256));
    }
    const int f0 = (c0 < K);
    const int f1 = (c1 < K);
    const unsigned long long m0 = __ballot(f0);
    const unsigned long long m1 = __ballot(f1);
    if (lane == 0) { s_ind[wave] = m0; s_ind[wave + 4] = m1; }
    __syncthreads();

    // c2m[l] = popcount of separator bits strictly below l; sorted separators
    #pragma unroll
    for (int k = 0; k < 2; ++k) {
        const int l  = tid + k * 256;
        const int wi = l >> 6;
        const unsigned long long lowmask = (1ull << (l & 63)) - 1ull;
        int cnt = 0;
        #pragma unroll
        for (int q = 0; q < 8; ++q) {
            const unsigned long long w = s_ind[q];
            cnt += (q < wi) ? __popcll(w) : ((q == wi) ? __popcll(w & lowmask) : 0);
        }
        s_c2m[l] = cnt;
        const int f = (k == 0) ? f0 : f1;
        if (f) s_sep[cnt] = l;   // cnt in [0, K): unique per separator
    }
    __syncthreads();

    // ---- Phase 3: bpm one-hot, float4-vectorized (6 float4 per l-row, M=24)
    float* bpm = out + (size_t)BATCH * MORPH * HID + (size_t)b * (SEQL * MORPH);
    for (int v = tid; v < SEQL * MORPH / 4; v += 256) {
        const int l  = v / 6;
        const int q  = v - l * 6;
        const int c  = s_c2m[l];
        const int mb = q * 4;
        const bool valid = (l < wl);
        float4 o;
        o.x = (valid && c == mb + 0 && mb + 0 < nm) ? 1.0f : 0.0f;
        o.y = (valid && c == mb + 1 && mb + 1 < nm) ? 1.0f : 0.0f;
        o.z = (valid && c == mb + 2 && mb + 2 < nm) ? 1.0f : 0.0f;
        o.w = (valid && c == mb + 3 && mb + 3 < nm) ? 1.0f : 0.0f;
        reinterpret_cast<float4*>(bpm)[v] = o;
    }

    // ---- Phase 4: menc segment sums; wave w handles morphemes m = w, w+4, ...
    float* mout = out + (size_t)b * (MORPH * HID);
    for (int m = wave; m < MORPH; m += 4) {
        float4 acc = {0.f, 0.f, 0.f, 0.f};
        if (m < nm) {
            const int start = (m == 0) ? 0 : (s_sep[m - 1] + 1);
            const int end   = (m < K) ? (s_sep[m] + 1) : wl;
            for (int l = start; l < end; ++l) {
                const float4 v = reinterpret_cast<const float4*>(werow + (size_t)l * HID)[lane];
                acc.x += v.x; acc.y += v.y; acc.z += v.z; acc.w += v.w;
            }
        }
        reinterpret_cast<float4*>(mout + m * HID)[lane] = acc;
    }
}

extern "C" void kernel_launch(void* const* d_in, const int* in_sizes, int n_in,
                              void* d_out, int out_size, void* d_ws, size_t ws_size,
                              hipStream_t stream) {
    const float* we     = (const float*)d_in[0];
    const int*   wlen   = (const int*)d_in[1];
    const int*   nmorph = (const int*)d_in[2];
    const float* Wv     = (const float*)d_in[3];
    const float* bias   = (const float*)d_in[4];
    float* out = (float*)d_out;
    morphseg_kernel<<<dim3(BATCH), dim3(256), 0, stream>>>(we, wlen, nmorph, Wv, bias, out);
}

// Round 2
// 85.577 us; speedup vs baseline: 1.8103x; 1.8103x over previous
//
#include <hip/hip_runtime.h>

namespace {
constexpr int BATCH = 512;
constexpr int SEQL  = 512;
constexpr int HID   = 256;
constexpr int MORPH = 24;
constexpr float NEGV = -1.0e9f;
constexpr int NTHR  = 1024;
constexpr int NWAVE = NTHR / 64;   // 16
}

// One block per batch row b. 1024 threads = 16 waves (2 blocks/CU => 100% occ).
// Phase 1: scores[l] = dot(we[b,l,:], W) + b0 for l < wl-1 (others NEG)
// Phase 2: exact stable top-(nm-1) rank, j-loop split across 2 threads/pos
// Phase 3: bpm one-hot write (float4) from c2m
// Phase 4: menc via row-parallel chunks + LDS atomic flush on morpheme change
extern "C" __global__ __launch_bounds__(1024)
void morphseg_kernel(const float* __restrict__ we,    // [B, L, H]
                     const int*   __restrict__ wlen,  // [B]
                     const int*   __restrict__ nmorph,// [B]
                     const float* __restrict__ Wv,    // [H]
                     const float* __restrict__ bias,  // [1]
                     float* __restrict__ out)         // menc [B*M*H] then bpm [B*L*M]
{
    const int b    = blockIdx.x;
    const int tid  = threadIdx.x;
    const int lane = tid & 63;
    const int wave = tid >> 6;

    __shared__ float s_scores[SEQL];                 // 2 KB
    __shared__ int   s_rankp[NTHR];                  // 4 KB partial ranks
    __shared__ unsigned long long s_ind[8];          // separator bitmask
    __shared__ int   s_c2m[SEQL];                    // 2 KB
    __shared__ float s_acc[MORPH][HID];              // 24 KB

    const int wl = wlen[b];
    const int nm = nmorph[b];
    const int K  = nm - 1;
    const float b0 = bias[0];
    const float* __restrict__ werow = we + (size_t)b * (SEQL * HID);

    // init: scores to NEG, acc to zero
    if (tid < SEQL) s_scores[tid] = NEGV;
    {
        float* af = &s_acc[0][0];
        for (int i = tid; i < MORPH * HID; i += NTHR) af[i] = 0.0f;
    }
    __syncthreads();

    // ---- Phase 1: scores, wave per row, only valid rows (l < wl-1)
    const float4 w4 = reinterpret_cast<const float4*>(Wv)[lane];
    const int nvalid = wl - 1;
    for (int l = wave; l < nvalid; l += NWAVE) {
        const float4 v = reinterpret_cast<const float4*>(werow + (size_t)l * HID)[lane];
        float p = v.x * w4.x + v.y * w4.y + v.z * w4.z + v.w * w4.w;
        #pragma unroll
        for (int off = 32; off >= 1; off >>= 1)
            p += __shfl_xor(p, off, 64);
        if (lane == 0) s_scores[l] = p + b0;
    }
    __syncthreads();

    // ---- Phase 2a: partial ranks. thread = (l = tid&511, jhalf = tid>>9)
    {
        const int l  = tid & (SEQL - 1);
        const int jh = tid >> 9;
        const float sl = s_scores[l];
        const int j0 = jh * (SEQL / 2);
        int c = 0;
        for (int j = j0; j < j0 + SEQL / 2; ++j) {
            const float sj = s_scores[j];   // uniform LDS broadcast
            c += (int)(sj > sl) | ((int)(sj == sl) & (int)(j < l));
        }
        s_rankp[tid] = c;
    }
    __syncthreads();

    // ---- Phase 2b: separator flags + ballot (stable top-K: rank < K)
    int f = 0;
    if (tid < SEQL) f = (s_rankp[tid] + s_rankp[tid + SEQL] < K) ? 1 : 0;
    const unsigned long long bal = __ballot(f);
    if (lane == 0 && wave < 8) s_ind[wave] = bal;
    __syncthreads();

    // ---- Phase 2c: c2m[l] = #separators strictly below l
    if (tid < SEQL) {
        const int wi = tid >> 6;
        const unsigned long long lowmask = (1ull << (tid & 63)) - 1ull;
        int cnt = 0;
        #pragma unroll
        for (int q = 0; q < 8; ++q) {
            const unsigned long long w = s_ind[q];
            cnt += (q < wi) ? __popcll(w) : ((q == wi) ? __popcll(w & lowmask) : 0);
        }
        s_c2m[tid] = cnt;
    }
    __syncthreads();

    // ---- Phase 3: bpm one-hot, float4-vectorized (6 float4 per l-row)
    float* __restrict__ bpm = out + (size_t)BATCH * MORPH * HID + (size_t)b * (SEQL * MORPH);
    for (int v = tid; v < SEQL * MORPH / 4; v += NTHR) {
        const int l  = v / 6;
        const int q  = v - l * 6;
        const int c  = s_c2m[l];
        const int mb = q * 4;
        const bool valid = (l < wl);
        float4 o;
        o.x = (valid && c == mb + 0 && mb + 0 < nm) ? 1.0f : 0.0f;
        o.y = (valid && c == mb + 1 && mb + 1 < nm) ? 1.0f : 0.0f;
        o.z = (valid && c == mb + 2 && mb + 2 < nm) ? 1.0f : 0.0f;
        o.w = (valid && c == mb + 3 && mb + 3 < nm) ? 1.0f : 0.0f;
        reinterpret_cast<float4*>(bpm)[v] = o;
    }

    // ---- Phase 4: menc, row-parallel: wave owns rows [wave*wl/16,(wave+1)*wl/16)
    {
        const int start = (wave * wl) / NWAVE;
        const int end   = ((wave + 1) * wl) / NWAVE;
        float4 acc = {0.f, 0.f, 0.f, 0.f};
        int mcur = -1;
        for (int l = start; l < end; ++l) {
            const int mm = s_c2m[l];           // wave-uniform broadcast
            if (mm != mcur) {                  // wave-uniform branch
                if (mcur >= 0) {
                    atomicAdd(&s_acc[mcur][lane * 4 + 0], acc.x);
                    atomicAdd(&s_acc[mcur][lane * 4 + 1], acc.y);
                    atomicAdd(&s_acc[mcur][lane * 4 + 2], acc.z);
                    atomicAdd(&s_acc[mcur][lane * 4 + 3], acc.w);
                    acc.x = acc.y = acc.z = acc.w = 0.f;
                }
                mcur = mm;
            }
            const float4 v = reinterpret_cast<const float4*>(werow + (size_t)l * HID)[lane];
            acc.x += v.x; acc.y += v.y; acc.z += v.z; acc.w += v.w;
        }
        if (mcur >= 0) {
            atomicAdd(&s_acc[mcur][lane * 4 + 0], acc.x);
            atomicAdd(&s_acc[mcur][lane * 4 + 1], acc.y);
            atomicAdd(&s_acc[mcur][lane * 4 + 2], acc.z);
            atomicAdd(&s_acc[mcur][lane * 4 + 3], acc.w);
        }
    }
    __syncthreads();

    // ---- write menc
    float* __restrict__ mout = out + (size_t)b * (MORPH * HID);
    {
        const float4* af = reinterpret_cast<const float4*>(&s_acc[0][0]);
        for (int i = tid; i < MORPH * HID / 4; i += NTHR)
            reinterpret_cast<float4*>(mout)[i] = af[i];
    }
}

extern "C" void kernel_launch(void* const* d_in, const int* in_sizes, int n_in,
                              void* d_out, int out_size, void* d_ws, size_t ws_size,
                              hipStream_t stream) {
    const float* we     = (const float*)d_in[0];
    const int*   wlen   = (const int*)d_in[1];
    const int*   nmorph = (const int*)d_in[2];
    const float* Wv     = (const float*)d_in[3];
    const float* bias   = (const float*)d_in[4];
    float* out = (float*)d_out;
    morphseg_kernel<<<dim3(BATCH), dim3(NTHR), 0, stream>>>(we, wlen, nmorph, Wv, bias, out);
}

// Round 3
// 64.625 us; speedup vs baseline: 2.3972x; 1.3242x over previous
//
#include <hip/hip_runtime.h>

namespace {
constexpr int BATCH = 512;
constexpr int SEQL  = 512;
constexpr int HID   = 256;
constexpr int MORPH = 24;
constexpr float NEGV = -1.0e9f;
constexpr int NTHR  = 1024;
constexpr int NWAVE = 16;
}

// One block per batch row b. 1024 threads = 16 waves (2 blocks/CU).
// Phase 1: scores -> order-keys (wave-per-row float4 matvec + shuffle reduce)
// Phase 2: exact stable top-(nm-1) via MSB radix-select (typ. 2 passes),
//          then separator flags + c2m via ballot/popcount prefix
// Phase 3: bpm one-hot write (float4)
// Phase 4: menc via row-parallel chunks + LDS atomic flush on morpheme change
extern "C" __global__ __launch_bounds__(1024)
void morphseg_kernel(const float* __restrict__ we,    // [B, L, H]
                     const int*   __restrict__ wlen,  // [B]
                     const int*   __restrict__ nmorph,// [B]
                     const float* __restrict__ Wv,    // [H]
                     const float* __restrict__ bias,  // [1]
                     float* __restrict__ out)         // menc [B*M*H] then bpm [B*L*M]
{
    const int b    = blockIdx.x;
    const int tid  = threadIdx.x;
    const int lane = tid & 63;
    const int wave = tid >> 6;

    __shared__ unsigned s_keys[SEQL];                // 2 KB order-preserved keys
    __shared__ int s_hist[256];                      // 1 KB radix histogram
    __shared__ int s_c2m[SEQL];                      // 2 KB
    __shared__ float s_acc[MORPH][HID];              // 24 KB
    __shared__ unsigned long long s_eqm[8];
    __shared__ unsigned long long s_ind[8];
    __shared__ unsigned s_p, s_T;
    __shared__ int s_Kr, s_KrF, s_done;

    const int wl = wlen[b];
    const int nm = nmorph[b];
    const int K  = nm - 1;
    const float b0 = bias[0];
    const float* __restrict__ werow = we + (size_t)b * (SEQL * HID);

    // monotone float->uint key (larger float => larger uint)
    auto okey = [](float f) -> unsigned {
        unsigned u = __float_as_uint(f);
        return u ^ (unsigned)(((int)u >> 31) | 0x80000000);
    };
    const unsigned KEYNEG = okey(NEGV);

    // ---- init
    if (tid < SEQL) s_keys[tid] = KEYNEG;
    {
        float* af = &s_acc[0][0];
        for (int i = tid; i < MORPH * HID; i += NTHR) af[i] = 0.0f;
    }
    if (tid == 0) { s_p = 0u; s_Kr = K; s_done = 0; }
    __syncthreads();

    // ---- Phase 1: keys for valid rows (l < wl-1); wave per row
    const float4 w4 = reinterpret_cast<const float4*>(Wv)[lane];
    const int nvalid = wl - 1;
    for (int l = wave; l < nvalid; l += NWAVE) {
        const float4 v = reinterpret_cast<const float4*>(werow + (size_t)l * HID)[lane];
        float p = v.x * w4.x + v.y * w4.y + v.z * w4.z + v.w * w4.w;
        #pragma unroll
        for (int off = 32; off >= 1; off >>= 1)
            p += __shfl_xor(p, off, 64);
        if (lane == 0) s_keys[l] = okey(p + b0);
    }
    __syncthreads();

    // ---- Phase 2: radix select, MSB-first, early exit on exact boundary
    int done = 0;
    for (int pass = 0; pass < 4 && !done; ++pass) {
        const int shift = 24 - 8 * pass;
        if (tid < 256) s_hist[tid] = 0;
        __syncthreads();
        if (tid < SEQL) {
            const unsigned k = s_keys[tid];
            const bool act = (pass == 0) ||
                             ((k >> (shift + 8)) == (s_p >> (shift + 8)));
            if (act) atomicAdd(&s_hist[(k >> shift) & 255], 1);
        }
        __syncthreads();
        if (wave == 0) {
            const int v0 = lane * 4;
            const int h0 = s_hist[v0], h1 = s_hist[v0 + 1];
            const int h2 = s_hist[v0 + 2], h3 = s_hist[v0 + 3];
            const int local = h0 + h1 + h2 + h3;
            int T = local;                       // inclusive suffix over lanes
            #pragma unroll
            for (int off = 1; off < 64; off <<= 1) {
                const int u = __shfl_down(T, off, 64);
                if (lane + off < 64) T += u;
            }
            const int A  = T - local;            // suffix strictly after this lane
            const int S3 = A + h3, S2 = S3 + h2, S1 = S2 + h1, S0 = S1 + h0;
            const int Kr = s_Kr;
            const unsigned p = s_p;
            // find unique v* with S(v*+1) < Kr <= S(v*)
            int v = -1, Sv = 0, Sv1 = 0;
            if (A  < Kr && Kr <= S3) { v = v0 + 3; Sv = S3; Sv1 = A;  }
            if (S3 < Kr && Kr <= S2) { v = v0 + 2; Sv = S2; Sv1 = S3; }
            if (S2 < Kr && Kr <= S1) { v = v0 + 1; Sv = S1; Sv1 = S2; }
            if (S1 < Kr && Kr <= S0) { v = v0 + 0; Sv = S0; Sv1 = S1; }
            if (v >= 0) {
                const unsigned pv = p | ((unsigned)v << shift);
                if (Sv == Kr) {                  // exact: select all >= pv
                    s_T = pv - 1u; s_KrF = 0; s_done = 1;
                } else if (shift == 0) {         // final: pv is the full key
                    s_T = pv; s_KrF = Kr - Sv1; s_done = 1;
                } else {
                    s_p = pv; s_Kr = Kr - Sv1;
                }
            }
        }
        __syncthreads();
        done = s_done;
    }

    // ---- flags: gt, plus lowest-index KrF of eq; then c2m
    const unsigned Tf = s_T;
    const int KrF = s_KrF;
    unsigned k = (tid < SEQL) ? s_keys[tid] : 0u;
    const bool gt = (tid < SEQL) && (k > Tf);
    const bool eq = (tid < SEQL) && (k == Tf);
    const unsigned long long eb = __ballot(eq);
    if (lane == 0 && wave < 8) s_eqm[wave] = eb;
    __syncthreads();
    int f = 0;
    if (tid < SEQL) {
        const unsigned long long lowmask = (1ull << lane) - 1ull;
        int r = 0;
        #pragma unroll
        for (int q = 0; q < 8; ++q) {
            const unsigned long long w = s_eqm[q];
            r += (q < wave) ? __popcll(w) : ((q == wave) ? __popcll(w & lowmask) : 0);
        }
        f = gt || (eq && r < KrF);
    }
    const unsigned long long fb = __ballot(f);
    if (lane == 0 && wave < 8) s_ind[wave] = fb;
    __syncthreads();
    if (tid < SEQL) {
        const unsigned long long lowmask = (1ull << lane) - 1ull;
        int cnt = 0;
        #pragma unroll
        for (int q = 0; q < 8; ++q) {
            const unsigned long long w = s_ind[q];
            cnt += (q < wave) ? __popcll(w) : ((q == wave) ? __popcll(w & lowmask) : 0);
        }
        s_c2m[tid] = cnt;
    }
    __syncthreads();

    // ---- Phase 3: bpm one-hot, float4-vectorized (6 float4 per l-row)
    float* __restrict__ bpm = out + (size_t)BATCH * MORPH * HID + (size_t)b * (SEQL * MORPH);
    for (int v = tid; v < SEQL * MORPH / 4; v += NTHR) {
        const int l  = v / 6;
        const int q  = v - l * 6;
        const int c  = s_c2m[l];
        const int mb = q * 4;
        const bool valid = (l < wl);
        float4 o;
        o.x = (valid && c == mb + 0 && mb + 0 < nm) ? 1.0f : 0.0f;
        o.y = (valid && c == mb + 1 && mb + 1 < nm) ? 1.0f : 0.0f;
        o.z = (valid && c == mb + 2 && mb + 2 < nm) ? 1.0f : 0.0f;
        o.w = (valid && c == mb + 3 && mb + 3 < nm) ? 1.0f : 0.0f;
        reinterpret_cast<float4*>(bpm)[v] = o;
    }

    // ---- Phase 4: menc, row-parallel: wave owns rows [wave*wl/16,(wave+1)*wl/16)
    {
        const int start = (wave * wl) / NWAVE;
        const int end   = ((wave + 1) * wl) / NWAVE;
        float4 acc = {0.f, 0.f, 0.f, 0.f};
        int mcur = -1;
        for (int l = start; l < end; ++l) {
            const int mm = s_c2m[l];           // wave-uniform broadcast
            if (mm != mcur) {                  // wave-uniform branch
                if (mcur >= 0) {
                    atomicAdd(&s_acc[mcur][lane * 4 + 0], acc.x);
                    atomicAdd(&s_acc[mcur][lane * 4 + 1], acc.y);
                    atomicAdd(&s_acc[mcur][lane * 4 + 2], acc.z);
                    atomicAdd(&s_acc[mcur][lane * 4 + 3], acc.w);
                    acc.x = acc.y = acc.z = acc.w = 0.f;
                }
                mcur = mm;
            }
            const float4 v = reinterpret_cast<const float4*>(werow + (size_t)l * HID)[lane];
            acc.x += v.x; acc.y += v.y; acc.z += v.z; acc.w += v.w;
        }
        if (mcur >= 0) {
            atomicAdd(&s_acc[mcur][lane * 4 + 0], acc.x);
            atomicAdd(&s_acc[mcur][lane * 4 + 1], acc.y);
            atomicAdd(&s_acc[mcur][lane * 4 + 2], acc.z);
            atomicAdd(&s_acc[mcur][lane * 4 + 3], acc.w);
        }
    }
    __syncthreads();

    // ---- write menc
    float* __restrict__ mout = out + (size_t)b * (MORPH * HID);
    {
        const float4* af = reinterpret_cast<const float4*>(&s_acc[0][0]);
        for (int i = tid; i < MORPH * HID / 4; i += NTHR)
            reinterpret_cast<float4*>(mout)[i] = af[i];
    }
}

extern "C" void kernel_launch(void* const* d_in, const int* in_sizes, int n_in,
                              void* d_out, int out_size, void* d_ws, size_t ws_size,
                              hipStream_t stream) {
    const float* we     = (const float*)d_in[0];
    const int*   wlen   = (const int*)d_in[1];
    const int*   nmorph = (const int*)d_in[2];
    const float* Wv     = (const float*)d_in[3];
    const float* bias   = (const float*)d_in[4];
    float* out = (float*)d_out;
    morphseg_kernel<<<dim3(BATCH), dim3(NTHR), 0, stream>>>(we, wlen, nmorph, Wv, bias, out);
}